// Round 5
// baseline (188.852 us; speedup 1.0000x reference)
//
#include <hip/hip_runtime.h>
#include <hip/hip_bf16.h>

// SupConLoss, B=8192, D=128, T=0.1. Output: single fp32 scalar.
//
// Pipeline (4 launches):
//   1) supcon_convert  — dtype detection (fp32 vs bf16 feats, i64 vs i32
//      labels) folded in; features -> bf16 ws copy (RTNE), labels -> int32;
//      zeroes class-sum buffer g and final accumulators.
//   2) supcon_classsum — g[c] = sum of bf16-rounded feature rows with label
//      c (fp32, LDS-staged per block, 16 blocks). Enables the p-via-dot
//      identity: p_i = sum_{pos j} s_ij = a_i . g[lab_i]  (exact modulo fp32
//      reorder, ~1e-6 on the loss).
//   3) supcon_main     — fused bf16-MFMA GEMM (F.F^T) + exp accumulation
//      ONLY (epilogue = fma + exp2 + add per element; no labels, no masks).
//      LDS double-buffered 64-col B tiles via global_load_lds(16B), XOR
//      swizzle applied on the GLOBAL source address (linear LDS dest +
//      inverse-swz source + swz read = same involution). 2-phase pipeline:
//      stage(next) before compute(cur), one drain+barrier per tile.
//      33KB LDS -> 4 blocks/CU resident (16 waves/CU). Diagonal raw dot
//      s_ii captured once per row.
//   4) supcon_reduce   — e partials + p_i = a_i.g[lab_i] dot -> loss. n_i
//      from exact label histogram. Diagonal terms removed exactly (e: same
//      exp2 instruction on same input; p: subtract diag). Last-block-atomic
//      finalization (ticket zeroed by convert -> graph-replay safe).
//
// Math: with ANY fixed shift M, per row i:
//   mean_log_prob_i = 10*p_i/n_i - M - log(sum_{j!=i} exp(s_ij - M))
// (shift cancels; M=10.5 >= max s_ij for unit-norm). exp folded to exp2.
//
// History:
//  r1: __launch_bounds__(256,4) forced VGPR=64 -> spill, FETCH 9.7->646MB,
//      46->215us. Never clamp below the live set.
//  r2: NC=16 + n_acc removal: main ~46 -> ~36us. Fixed 41us/268MB harness
//      workspace-poison fill in the timed region (uncontrollable floor).
//  r3: no-LDS direct-L2 reads: main 68.7us. Latency-bound serial chain;
//      L2-residency kills staging BW cost, not latency cost.
//  r4: 2-phase pipelined staging: main ~35us (-1.5 only). Epilogue-VALU
//      bound (5 VALU + 1 trans per elem), not staging-bound -> this round
//      removes 3/5 VALU ops via the class-sum identity + 4-block residency.

#define BB 8192
#define DD 128
#define NCLS 100
#define NC 16                // column chunks (grid.x): 1024 blocks, 4/CU
#define COLCHUNK (BB / NC)   // 512 cols per WG
#define TILEC 64             // cols per staged tile (16KB)
#define ITERS (COLCHUNK / TILEC)
#define TEMP_INV 10.0f
#define MSHIFT 10.5f
#define C1F 14.426950408889634f    /* 10*log2(e)    */
#define C2F -15.148297929334116f   /* -10.5*log2(e) */

typedef __bf16 bf16x8 __attribute__((ext_vector_type(8)));
typedef float floatx4 __attribute__((ext_vector_type(4)));

__device__ inline float fast_exp2(float x) {
#if __has_builtin(__builtin_amdgcn_exp2f)
    return __builtin_amdgcn_exp2f(x);
#else
    return exp2f(x);
#endif
}

__device__ inline unsigned short f2bf(float f) {           // RTNE fp32->bf16
    unsigned u = __float_as_uint(f);
    return (unsigned short)((u + 0x7FFFu + ((u >> 16) & 1u)) >> 16);
}

__device__ inline float bf2f(unsigned short s) {
    return __uint_as_float(((unsigned)s) << 16);
}

__device__ inline void gload_lds16(const void* g, void* l) {
    __builtin_amdgcn_global_load_lds(
        (const __attribute__((address_space(1))) void*)g,
        (__attribute__((address_space(3))) void*)l, 16, 0, 0);
}

// ---- 1) canonicalize (+ detect + zero g/finals) ----
__global__ __launch_bounds__(256) void supcon_convert(
    const void* __restrict__ fin, const void* __restrict__ lin,
    unsigned short* __restrict__ fbf, int* __restrict__ lab,
    float* __restrict__ g, float* __restrict__ accbuf)
{
    // Per-wave dtype detection: every wave reads the same 128-short feature
    // header and 128-int label header, butterfly-reduces across its own 64
    // lanes -> every thread holds the verdict, no LDS/sync needed.
    int lane = threadIdx.x & 63;
    unsigned ue = ((unsigned)((const unsigned short*)fin)[2 * lane]) << 16;
    float fe = __uint_as_float(ue);
    float ve = fe * fe;
    int odd_or = ((const int*)lin)[2 * lane + 1];
#pragma unroll
    for (int m = 1; m < 64; m <<= 1) {
        ve += __shfl_xor(ve, m, 64);
        odd_or |= __shfl_xor(odd_or, m, 64);
    }
    // true bf16 unit rows: sum sq of 64 even slots of row 0 is ~0.5.
    bool f_bf16 = (ve > 0.05f) && (ve < 4.0f);   // NaN-safe: NaN -> false
    bool l_i64  = (odd_or == 0);

    int gid = blockIdx.x * 256 + threadIdx.x;    // 262144 threads x 4 elements
    if (!f_bf16) {
        float4 v = ((const float4*)fin)[gid];
        ushort4 o;
        o.x = f2bf(v.x); o.y = f2bf(v.y); o.z = f2bf(v.z); o.w = f2bf(v.w);
        ((ushort4*)fbf)[gid] = o;
    } else {
        ((ushort4*)fbf)[gid] = ((const ushort4*)fin)[gid];
    }
    if (blockIdx.x < 32) {
        int li = blockIdx.x * 256 + threadIdx.x;
        const int* L = (const int*)lin;
        lab[li] = l_i64 ? L[2 * li] : L[li];
    }
    if (blockIdx.x == 0) {
        for (int i = threadIdx.x; i < NCLS * DD; i += 256) g[i] = 0.0f;
        if (threadIdx.x == 0) {                  // zero last-block finals
            accbuf[0] = 0.0f;                    // loss sum
            accbuf[1] = 0.0f;                    // valid count
            ((unsigned*)accbuf)[2] = 0u;         // ticket
        }
    }
}

// ---- 2) per-class feature sums g[c][d] (fp32, from bf16-rounded rows) ----
#define CS_BLOCKS 16
#define CS_ROWS (BB / CS_BLOCKS)     // 512 rows per block
__global__ __launch_bounds__(256) void supcon_classsum(
    const unsigned short* __restrict__ Fb, const int* __restrict__ lab,
    float* __restrict__ g)
{
    __shared__ float gl[NCLS * DD];              // 51.2 KB
    for (int i = threadIdx.x; i < NCLS * DD; i += 256) gl[i] = 0.0f;
    __syncthreads();

    int base = blockIdx.x * CS_ROWS;
    int d  = threadIdx.x & 127;                  // dim
    int rh = threadIdx.x >> 7;                   // row half (0/1)
    // Each wave handles one row x 64 dims per pass: uniform label read,
    // contiguous 128B feature read.
    for (int j0 = 0; j0 < CS_ROWS; j0 += 2) {
        int j = base + j0 + rh;
        int c = lab[j];
        float v = bf2f(Fb[(size_t)j * DD + d]);
        atomicAdd(&gl[c * DD + d], v);
    }
    __syncthreads();
    for (int i = threadIdx.x; i < NCLS * DD; i += 256)
        atomicAdd(&g[i], gl[i]);
}

// Stage one 64-col B tile (16KB) into ldsB[bsel] via global_load_lds.
// LDS dest is LINEAR (wave-uniform base + lane*16, hardware rule); the XOR
// swizzle is applied to the SOURCE address. Dest slot d of row r receives
// source chunk d^(r&15); the swizzled ds_read of chunk k at slot k^(r&15)
// therefore returns chunk k — identical values to a swizzled ds_write path.
#define STAGE_B(itx, bsel)                                                   \
    {                                                                        \
        const unsigned char* gB =                                            \
            Fbc + (size_t)(colchunkbase + (itx) * TILEC) * 256;              \
        unsigned char* lb = &ldsB[bsel][0];                                  \
        _Pragma("unroll")                                                    \
        for (int r = 0; r < 4; ++r) {                                        \
            int off = r * 4096 + tid * 16;                                   \
            int row = off >> 8;                                              \
            int gg  = (off >> 4) & 15;                                       \
            int gs  = gg ^ (row & 15);                                       \
            gload_lds16(gB + row * 256 + gs * 16, lb + off);                 \
        }                                                                    \
    }

// ---- 3) fused GEMM + exp partials (2-phase pipelined, e-only epilogue) ----
__global__ __launch_bounds__(256, 2) void supcon_main(
    const unsigned short* __restrict__ Fb,
    float* __restrict__ e_part, float* __restrict__ diag)
{
    __shared__ unsigned char ldsB[2][16384];      // double-buffered 64-col tiles
    __shared__ float red[128][2];

    const int tid  = threadIdx.x;
    const int lane = tid & 63;
    const int wid  = tid >> 6;
    const int wrow = wid >> 1;
    const int wcol = wid & 1;
    const int quad = lane >> 4;
    const int l16  = lane & 15;

    const int chunk   = blockIdx.x;
    const int rowbase = blockIdx.y * 128;
    const int colchunkbase = chunk * COLCHUNK;

    const unsigned char* Fbc = (const unsigned char*)Fb;

    // Prologue: stage tile 0; A-frag loads (direct from L2) overlap it.
    STAGE_B(0, 0);

    bf16x8 afrag[4][4];
#pragma unroll
    for (int ti = 0; ti < 4; ++ti) {
        int row = rowbase + wrow * 64 + ti * 16 + l16;
        const unsigned char* gA = Fbc + (size_t)row * 256 + quad * 16;
#pragma unroll
        for (int k = 0; k < 4; ++k)
            afrag[ti][k] = *(const bf16x8*)(gA + k * 64);
    }

    float e_acc[16];
#pragma unroll
    for (int i = 0; i < 16; ++i) e_acc[i] = 0.0f;

    __syncthreads();   // drains tile-0 staging (vmcnt(0)) + barrier

    int cur = 0;
    for (int it = 0; it < ITERS; ++it) {
        // Issue next tile's stage FIRST: latency hides under this tile's
        // MFMA+epilogue.
        if (it + 1 < ITERS) STAGE_B(it + 1, cur ^ 1);

        int colbase = colchunkbase + it * TILEC;
        const unsigned char* lb = &ldsB[cur][0];

#pragma unroll
        for (int tj = 0; tj < 2; ++tj) {
            int coll = wcol * 32 + tj * 16 + l16;   // B[n=l16][k=quad*8+j]
            bf16x8 bfrag[4];
#pragma unroll
            for (int k = 0; k < 4; ++k) {
                int gg = k * 4 + quad;
                int gs = gg ^ (coll & 15);
                bfrag[k] = *(const bf16x8*)(lb + coll * 256 + gs * 16);
            }
            floatx4 acc[4];
#pragma unroll
            for (int ti = 0; ti < 4; ++ti) acc[ti] = (floatx4){0.f, 0.f, 0.f, 0.f};
#pragma unroll
            for (int k = 0; k < 4; ++k)
#pragma unroll
                for (int ti = 0; ti < 4; ++ti)
                    acc[ti] = __builtin_amdgcn_mfma_f32_16x16x32_bf16(
                        afrag[ti][k], bfrag[k], acc[ti], 0, 0, 0);

            // Diagonal capture: wave-uniform, rare (once per 64 diag cols).
            // Static indexing of acc (rule: no runtime ext_vector index).
            {
                int ctb = colbase + wcol * 32 + tj * 16;
                unsigned u = (unsigned)(ctb - (rowbase + wrow * 64));
                if (u < 64u) {
#pragma unroll
                    for (int ti2 = 0; ti2 < 4; ++ti2) {
                        if (u == (unsigned)(ti2 * 16)) {
#pragma unroll
                            for (int r = 0; r < 4; ++r)
                                if (l16 == quad * 4 + r)
                                    diag[ctb + l16] = acc[ti2][r];
                        }
                    }
                }
            }

#pragma unroll
            for (int ti = 0; ti < 4; ++ti) {
#pragma unroll
                for (int r = 0; r < 4; ++r) {
                    // C/D: D[row=quad*4+r][col=l16] (m89/m91 verified)
                    // 2 VALU + 1 trans per elem: fma, exp2, add.
                    float a = acc[ti][r];                        // raw dot
                    e_acc[ti * 4 + r] += fast_exp2(__builtin_fmaf(a, C1F, C2F));
                }
            }
        }
        __syncthreads();   // drain next-tile loads + all waves done reading cur
        cur ^= 1;
    }

    // reduce across 16 column-lanes (xor over lane bits 0..3)
#pragma unroll
    for (int i = 0; i < 16; ++i) {
        float e = e_acc[i];
#pragma unroll
        for (int m = 1; m < 16; m <<= 1) e += __shfl_xor(e, m, 64);
        if (l16 == 0) {
            int row_local = wrow * 64 + (i >> 2) * 16 + quad * 4 + (i & 3);
            red[row_local][wcol] = e;
        }
    }
    __syncthreads();

    if (tid < 128) {
        size_t idx = (size_t)chunk * BB + (rowbase + tid);
        e_part[idx] = red[tid][0] + red[tid][1];
    }
}

// ---- 4) e partials + p-dot -> scalar loss ----
__global__ __launch_bounds__(256) void supcon_reduce(
    const float* __restrict__ e_part, const unsigned short* __restrict__ Fb,
    const int* __restrict__ labels, const float* __restrict__ g,
    const float* __restrict__ diag,
    float* __restrict__ accbuf, float* __restrict__ out)
{
    // Exact per-class counts over the whole batch (labels in [0,100)).
    __shared__ int cnt[128];
    if (threadIdx.x < 128) cnt[threadIdx.x] = 0;
    __syncthreads();
    for (int i = threadIdx.x; i < BB; i += 256)
        atomicAdd(&cnt[labels[i]], 1);
    __syncthreads();

    int row = blockIdx.x * 256 + threadIdx.x;    // grid 32
    float e = 0.f;
#pragma unroll
    for (int c = 0; c < NC; ++c)
        e += e_part[(size_t)c * BB + row];

    int cls = labels[row];

    // p_i = a_i . g[lab_i]  (bf16-rounded features, fp32 class sums)
    const unsigned short* fr = Fb + (size_t)row * DD;
    const float* gr = g + cls * DD;
    float p0 = 0.f, p1 = 0.f;
#pragma unroll
    for (int q = 0; q < 8; ++q) {
        uint4  u  = ((const uint4*)fr)[q];        // 8 bf16
        float4 ga = ((const float4*)gr)[2 * q];
        float4 gb = ((const float4*)gr)[2 * q + 1];
        p0 = __builtin_fmaf(__uint_as_float(u.x << 16),          ga.x, p0);
        p1 = __builtin_fmaf(__uint_as_float(u.x & 0xFFFF0000u),  ga.y, p1);
        p0 = __builtin_fmaf(__uint_as_float(u.y << 16),          ga.z, p0);
        p1 = __builtin_fmaf(__uint_as_float(u.y & 0xFFFF0000u),  ga.w, p1);
        p0 = __builtin_fmaf(__uint_as_float(u.z << 16),          gb.x, p0);
        p1 = __builtin_fmaf(__uint_as_float(u.z & 0xFFFF0000u),  gb.y, p1);
        p0 = __builtin_fmaf(__uint_as_float(u.w << 16),          gb.z, p0);
        p1 = __builtin_fmaf(__uint_as_float(u.w & 0xFFFF0000u),  gb.w, p1);
    }
    float p = p0 + p1;

    // exact diagonal removal (e: same exp2 instruction on same input as main)
    float d = diag[row];
    e -= fast_exp2(__builtin_fmaf(d, C1F, C2F));
    p -= d;
    int n_i = cnt[cls] - 1;                      // integer-exact positive count

    float contrib = 0.f, vld = 0.f;
    if (n_i > 0) {
        vld = 1.0f;
        contrib = -(p * TEMP_INV / (float)n_i - MSHIFT - logf(e));
    }
#pragma unroll
    for (int m = 1; m < 64; m <<= 1) {
        contrib += __shfl_xor(contrib, m, 64);
        vld     += __shfl_xor(vld, m, 64);
    }
    __shared__ float rl[4], rv[4];
    int lane = threadIdx.x & 63, w = threadIdx.x >> 6;
    if (lane == 0) { rl[w] = contrib; rv[w] = vld; }
    __syncthreads();
    if (threadIdx.x == 0) {
        float L = rl[0] + rl[1] + rl[2] + rl[3];
        float V = rv[0] + rv[1] + rv[2] + rv[3];
        atomicAdd(&accbuf[0], L);
        atomicAdd(&accbuf[1], V);
        __threadfence();
        unsigned t = atomicAdd((unsigned*)accbuf + 2, 1u);
        if (t == 31u) {                      // last block: all adds fenced+done
            float Ls = atomicAdd(&accbuf[0], 0.0f);
            float Vs = atomicAdd(&accbuf[1], 0.0f);
            out[0] = (Vs > 0.5f) ? (Ls / Vs) : 0.0f;
        }
    }
}

extern "C" void kernel_launch(void* const* d_in, const int* in_sizes, int n_in,
                              void* d_out, int out_size, void* d_ws, size_t ws_size,
                              hipStream_t stream)
{
    const void* Fin = d_in[0];
    const void* Lin = d_in[1];

    // ws layout (~2.7 MB)
    unsigned short* fbf = (unsigned short*)d_ws;                          // 2 MB bf16 copy
    int*   lab      = (int*)((char*)d_ws + (size_t)BB * DD * 2);          // 32 KB
    float* e_part   = (float*)((char*)lab + (size_t)BB * 4);              // NC*B floats (512 KB)
    float* diag     = e_part + (size_t)NC * BB;                           // B floats
    float* g        = diag + BB;                                          // 100*128 floats
    float* accbuf   = g + NCLS * DD;                                      // 3 slots

    supcon_convert<<<BB * DD / 4 / 256, 256, 0, stream>>>(Fin, Lin, fbf, lab, g, accbuf);

    supcon_classsum<<<CS_BLOCKS, 256, 0, stream>>>(fbf, lab, g);

    dim3 grid(NC, BB / 128);
    supcon_main<<<grid, 256, 0, stream>>>(fbf, e_part, diag);

    supcon_reduce<<<32, 256, 0, stream>>>(e_part, fbf, lab, g, diag, accbuf, (float*)d_out);
}

// Round 6
// 138.651 us; speedup vs baseline: 1.3621x; 1.3621x over previous
//
#include <hip/hip_runtime.h>
#include <hip/hip_bf16.h>

// SupConLoss, B=8192, D=128, T=0.1. Output: single fp32 scalar.
//
// Pipeline (4 launches):
//   1) supcon_convert  — dtype detection (fp32 vs bf16 feats, i64 vs i32
//      labels) folded in; features -> bf16 ws copy (RTNE), labels -> int32;
//      zeroes class-sum buffer g and final accumulators.
//   2) supcon_classsum — g[c] = sum of bf16-rounded feature rows with label
//      c (fp32). Class-parallel uniform scan: 100 classes x 8 row-chunks,
//      128 threads (dim d); wave-uniform label compares skip non-matching
//      rows entirely; one global atomicAdd per (block,dim). Enables the
//      p-via-dot identity: p_i = sum_{pos j} s_ij = a_i . g[lab_i]
//      (exact modulo fp32 reorder, ~1e-6 on the loss).
//   3) supcon_main     — fused bf16-MFMA GEMM (F.F^T) + exp accumulation
//      ONLY (epilogue = fma + exp2 + add per element; no labels, no masks).
//      LDS double-buffered 64-col B tiles via global_load_lds(16B), XOR
//      swizzle applied on the GLOBAL source address (linear LDS dest +
//      inverse-swz source + swz read = same involution). 2-phase pipeline:
//      stage(next) before compute(cur), one drain+barrier per tile.
//      33KB LDS -> 4 blocks/CU resident (16 waves/CU). Diagonal raw dot
//      s_ii captured once per row.
//   4) supcon_reduce   — e partials + p_i = a_i.g[lab_i] dot (ALL 128 dims)
//      -> loss. n_i from exact label histogram. Diagonal terms removed
//      exactly (e: same exp2 instruction on same input; p: subtract diag).
//      Last-block-atomic finalization (ticket zeroed by convert ->
//      graph-replay safe).
//
// Math: with ANY fixed shift M, per row i:
//   mean_log_prob_i = 10*p_i/n_i - M - log(sum_{j!=i} exp(s_ij - M))
// (shift cancels; M=10.5 >= max s_ij for unit-norm). exp folded to exp2.
//
// History:
//  r1: __launch_bounds__(256,4) forced VGPR=64 -> spill, FETCH 9.7->646MB,
//      46->215us. Never clamp below the live set.
//  r2: NC=16 + n_acc removal: main ~46 -> ~36us. Fixed 41us/268MB harness
//      workspace-poison fill in the timed region (uncontrollable floor).
//  r3: no-LDS direct-L2 reads: main 68.7us. Latency-bound serial chain.
//  r4: 2-phase pipelined staging: main ~35us. Epilogue-VALU bound.
//  r5: class-sum identity (epilogue -> fma+exp2+add) BUT (a) classsum was
//      16-block LDS-atomic latency-bound: 88us; (b) reduce's p-dot covered
//      only 64/128 dims -> systematic +0.0625 loss bias (half the self-term
//      vs full diag subtract). Both fixed this round.

#define BB 8192
#define DD 128
#define NCLS 100
#define NC 16                // column chunks (grid.x): 1024 blocks, 4/CU
#define COLCHUNK (BB / NC)   // 512 cols per WG
#define TILEC 64             // cols per staged tile (16KB)
#define ITERS (COLCHUNK / TILEC)
#define TEMP_INV 10.0f
#define MSHIFT 10.5f
#define C1F 14.426950408889634f    /* 10*log2(e)    */
#define C2F -15.148297929334116f   /* -10.5*log2(e) */

typedef __bf16 bf16x8 __attribute__((ext_vector_type(8)));
typedef float floatx4 __attribute__((ext_vector_type(4)));

__device__ inline float fast_exp2(float x) {
#if __has_builtin(__builtin_amdgcn_exp2f)
    return __builtin_amdgcn_exp2f(x);
#else
    return exp2f(x);
#endif
}

__device__ inline unsigned short f2bf(float f) {           // RTNE fp32->bf16
    unsigned u = __float_as_uint(f);
    return (unsigned short)((u + 0x7FFFu + ((u >> 16) & 1u)) >> 16);
}

__device__ inline float bf2f(unsigned short s) {
    return __uint_as_float(((unsigned)s) << 16);
}

__device__ inline void gload_lds16(const void* g, void* l) {
    __builtin_amdgcn_global_load_lds(
        (const __attribute__((address_space(1))) void*)g,
        (__attribute__((address_space(3))) void*)l, 16, 0, 0);
}

// ---- 1) canonicalize (+ detect + zero g/finals) ----
__global__ __launch_bounds__(256) void supcon_convert(
    const void* __restrict__ fin, const void* __restrict__ lin,
    unsigned short* __restrict__ fbf, int* __restrict__ lab,
    float* __restrict__ g, float* __restrict__ accbuf)
{
    // Per-wave dtype detection: every wave reads the same 128-short feature
    // header and 128-int label header, butterfly-reduces across its own 64
    // lanes -> every thread holds the verdict, no LDS/sync needed.
    int lane = threadIdx.x & 63;
    unsigned ue = ((unsigned)((const unsigned short*)fin)[2 * lane]) << 16;
    float fe = __uint_as_float(ue);
    float ve = fe * fe;
    int odd_or = ((const int*)lin)[2 * lane + 1];
#pragma unroll
    for (int m = 1; m < 64; m <<= 1) {
        ve += __shfl_xor(ve, m, 64);
        odd_or |= __shfl_xor(odd_or, m, 64);
    }
    // true bf16 unit rows: sum sq of 64 even slots of row 0 is ~0.5.
    bool f_bf16 = (ve > 0.05f) && (ve < 4.0f);   // NaN-safe: NaN -> false
    bool l_i64  = (odd_or == 0);

    int gid = blockIdx.x * 256 + threadIdx.x;    // 262144 threads x 4 elements
    if (!f_bf16) {
        float4 v = ((const float4*)fin)[gid];
        ushort4 o;
        o.x = f2bf(v.x); o.y = f2bf(v.y); o.z = f2bf(v.z); o.w = f2bf(v.w);
        ((ushort4*)fbf)[gid] = o;
    } else {
        ((ushort4*)fbf)[gid] = ((const ushort4*)fin)[gid];
    }
    if (blockIdx.x < 32) {
        int li = blockIdx.x * 256 + threadIdx.x;
        const int* L = (const int*)lin;
        lab[li] = l_i64 ? L[2 * li] : L[li];
    }
    if (blockIdx.x == 0) {
        for (int i = threadIdx.x; i < NCLS * DD; i += 256) g[i] = 0.0f;
        if (threadIdx.x == 0) {                  // zero last-block finals
            accbuf[0] = 0.0f;                    // loss sum
            accbuf[1] = 0.0f;                    // valid count
            ((unsigned*)accbuf)[2] = 0u;         // ticket
        }
    }
}

// ---- 2) per-class feature sums g[c][d] (class-parallel uniform scan) ----
#define CS_CHUNKS 8
#define CS_ROWS (BB / CS_CHUNKS)     // 1024 rows per chunk
__global__ __launch_bounds__(128) void supcon_classsum(
    const unsigned short* __restrict__ Fb, const int* __restrict__ lab,
    float* __restrict__ g)
{
    const int c    = blockIdx.x / CS_CHUNKS;     // class 0..99
    const int base = (blockIdx.x % CS_CHUNKS) * CS_ROWS;
    const int d    = threadIdx.x;                // dim 0..127
    float acc = 0.0f;
    // Wave-uniform label scan: the compare is uniform across the block, so
    // non-matching rows cost only the (L1-broadcast) int4 load + 4 s_cmp;
    // the 256B feature load happens only for ~10 matching rows per chunk.
    for (int j = base; j < base + CS_ROWS; j += 4) {
        int4 l4 = *(const int4*)&lab[j];
        if (l4.x == c) acc += bf2f(Fb[(size_t)(j + 0) * DD + d]);
        if (l4.y == c) acc += bf2f(Fb[(size_t)(j + 1) * DD + d]);
        if (l4.z == c) acc += bf2f(Fb[(size_t)(j + 2) * DD + d]);
        if (l4.w == c) acc += bf2f(Fb[(size_t)(j + 3) * DD + d]);
    }
    atomicAdd(&g[c * DD + d], acc);              // 8 adds per address total
}

// Stage one 64-col B tile (16KB) into ldsB[bsel] via global_load_lds.
// LDS dest is LINEAR (wave-uniform base + lane*16, hardware rule); the XOR
// swizzle is applied to the SOURCE address. Dest slot d of row r receives
// source chunk d^(r&15); the swizzled ds_read of chunk k at slot k^(r&15)
// therefore returns chunk k — identical values to a swizzled ds_write path.
#define STAGE_B(itx, bsel)                                                   \
    {                                                                        \
        const unsigned char* gB =                                            \
            Fbc + (size_t)(colchunkbase + (itx) * TILEC) * 256;              \
        unsigned char* lb = &ldsB[bsel][0];                                  \
        _Pragma("unroll")                                                    \
        for (int r = 0; r < 4; ++r) {                                        \
            int off = r * 4096 + tid * 16;                                   \
            int row = off >> 8;                                              \
            int gg  = (off >> 4) & 15;                                       \
            int gs  = gg ^ (row & 15);                                       \
            gload_lds16(gB + row * 256 + gs * 16, lb + off);                 \
        }                                                                    \
    }

// ---- 3) fused GEMM + exp partials (2-phase pipelined, e-only epilogue) ----
__global__ __launch_bounds__(256, 2) void supcon_main(
    const unsigned short* __restrict__ Fb,
    float* __restrict__ e_part, float* __restrict__ diag)
{
    __shared__ unsigned char ldsB[2][16384];      // double-buffered 64-col tiles
    __shared__ float red[128][2];

    const int tid  = threadIdx.x;
    const int lane = tid & 63;
    const int wid  = tid >> 6;
    const int wrow = wid >> 1;
    const int wcol = wid & 1;
    const int quad = lane >> 4;
    const int l16  = lane & 15;

    const int chunk   = blockIdx.x;
    const int rowbase = blockIdx.y * 128;
    const int colchunkbase = chunk * COLCHUNK;

    const unsigned char* Fbc = (const unsigned char*)Fb;

    // Prologue: stage tile 0; A-frag loads (direct from L2) overlap it.
    STAGE_B(0, 0);

    bf16x8 afrag[4][4];
#pragma unroll
    for (int ti = 0; ti < 4; ++ti) {
        int row = rowbase + wrow * 64 + ti * 16 + l16;
        const unsigned char* gA = Fbc + (size_t)row * 256 + quad * 16;
#pragma unroll
        for (int k = 0; k < 4; ++k)
            afrag[ti][k] = *(const bf16x8*)(gA + k * 64);
    }

    float e_acc[16];
#pragma unroll
    for (int i = 0; i < 16; ++i) e_acc[i] = 0.0f;

    __syncthreads();   // drains tile-0 staging (vmcnt(0)) + barrier

    int cur = 0;
    for (int it = 0; it < ITERS; ++it) {
        // Issue next tile's stage FIRST: latency hides under this tile's
        // MFMA+epilogue.
        if (it + 1 < ITERS) STAGE_B(it + 1, cur ^ 1);

        int colbase = colchunkbase + it * TILEC;
        const unsigned char* lb = &ldsB[cur][0];

#pragma unroll
        for (int tj = 0; tj < 2; ++tj) {
            int coll = wcol * 32 + tj * 16 + l16;   // B[n=l16][k=quad*8+j]
            bf16x8 bfrag[4];
#pragma unroll
            for (int k = 0; k < 4; ++k) {
                int gg = k * 4 + quad;
                int gs = gg ^ (coll & 15);
                bfrag[k] = *(const bf16x8*)(lb + coll * 256 + gs * 16);
            }
            floatx4 acc[4];
#pragma unroll
            for (int ti = 0; ti < 4; ++ti) acc[ti] = (floatx4){0.f, 0.f, 0.f, 0.f};
#pragma unroll
            for (int k = 0; k < 4; ++k)
#pragma unroll
                for (int ti = 0; ti < 4; ++ti)
                    acc[ti] = __builtin_amdgcn_mfma_f32_16x16x32_bf16(
                        afrag[ti][k], bfrag[k], acc[ti], 0, 0, 0);

            // Diagonal capture: wave-uniform, rare (once per 64 diag cols).
            // Static indexing of acc (rule: no runtime ext_vector index).
            {
                int ctb = colbase + wcol * 32 + tj * 16;
                unsigned u = (unsigned)(ctb - (rowbase + wrow * 64));
                if (u < 64u) {
#pragma unroll
                    for (int ti2 = 0; ti2 < 4; ++ti2) {
                        if (u == (unsigned)(ti2 * 16)) {
#pragma unroll
                            for (int r = 0; r < 4; ++r)
                                if (l16 == quad * 4 + r)
                                    diag[ctb + l16] = acc[ti2][r];
                        }
                    }
                }
            }

#pragma unroll
            for (int ti = 0; ti < 4; ++ti) {
#pragma unroll
                for (int r = 0; r < 4; ++r) {
                    // C/D: D[row=quad*4+r][col=l16] (m89/m91 verified)
                    // 2 VALU + 1 trans per elem: fma, exp2, add.
                    float a = acc[ti][r];                        // raw dot
                    e_acc[ti * 4 + r] += fast_exp2(__builtin_fmaf(a, C1F, C2F));
                }
            }
        }
        __syncthreads();   // drain next-tile loads + all waves done reading cur
        cur ^= 1;
    }

    // reduce across 16 column-lanes (xor over lane bits 0..3)
#pragma unroll
    for (int i = 0; i < 16; ++i) {
        float e = e_acc[i];
#pragma unroll
        for (int m = 1; m < 16; m <<= 1) e += __shfl_xor(e, m, 64);
        if (l16 == 0) {
            int row_local = wrow * 64 + (i >> 2) * 16 + quad * 4 + (i & 3);
            red[row_local][wcol] = e;
        }
    }
    __syncthreads();

    if (tid < 128) {
        size_t idx = (size_t)chunk * BB + (rowbase + tid);
        e_part[idx] = red[tid][0] + red[tid][1];
    }
}

// ---- 4) e partials + p-dot -> scalar loss ----
__global__ __launch_bounds__(256) void supcon_reduce(
    const float* __restrict__ e_part, const unsigned short* __restrict__ Fb,
    const int* __restrict__ labels, const float* __restrict__ g,
    const float* __restrict__ diag,
    float* __restrict__ accbuf, float* __restrict__ out)
{
    // Exact per-class counts over the whole batch (labels in [0,100)).
    __shared__ int cnt[128];
    if (threadIdx.x < 128) cnt[threadIdx.x] = 0;
    __syncthreads();
    for (int i = threadIdx.x; i < BB; i += 256)
        atomicAdd(&cnt[labels[i]], 1);
    __syncthreads();

    int row = blockIdx.x * 256 + threadIdx.x;    // grid 32
    float e = 0.f;
#pragma unroll
    for (int c = 0; c < NC; ++c)
        e += e_part[(size_t)c * BB + row];

    int cls = labels[row];

    // p_i = a_i . g[lab_i]  (bf16-rounded features, fp32 class sums).
    // 16 x uint4 = all 128 dims (r5 bug: q<8 covered only 64 dims ->
    // half self-term vs full diag subtract -> systematic +0.0625 bias).
    const unsigned short* fr = Fb + (size_t)row * DD;
    const float* gr = g + cls * DD;
    float p0 = 0.f, p1 = 0.f;
#pragma unroll
    for (int q = 0; q < 16; ++q) {
        uint4  u  = ((const uint4*)fr)[q];        // 8 bf16
        float4 ga = ((const float4*)gr)[2 * q];
        float4 gb = ((const float4*)gr)[2 * q + 1];
        p0 = __builtin_fmaf(__uint_as_float(u.x << 16),          ga.x, p0);
        p1 = __builtin_fmaf(__uint_as_float(u.x & 0xFFFF0000u),  ga.y, p1);
        p0 = __builtin_fmaf(__uint_as_float(u.y << 16),          ga.z, p0);
        p1 = __builtin_fmaf(__uint_as_float(u.y & 0xFFFF0000u),  ga.w, p1);
        p0 = __builtin_fmaf(__uint_as_float(u.z << 16),          gb.x, p0);
        p1 = __builtin_fmaf(__uint_as_float(u.z & 0xFFFF0000u),  gb.y, p1);
        p0 = __builtin_fmaf(__uint_as_float(u.w << 16),          gb.z, p0);
        p1 = __builtin_fmaf(__uint_as_float(u.w & 0xFFFF0000u),  gb.w, p1);
    }
    float p = p0 + p1;

    // exact diagonal removal (e: same exp2 instruction on same input as main)
    float d = diag[row];
    e -= fast_exp2(__builtin_fmaf(d, C1F, C2F));
    p -= d;
    int n_i = cnt[cls] - 1;                      // integer-exact positive count

    float contrib = 0.f, vld = 0.f;
    if (n_i > 0) {
        vld = 1.0f;
        contrib = -(p * TEMP_INV / (float)n_i - MSHIFT - logf(e));
    }
#pragma unroll
    for (int m = 1; m < 64; m <<= 1) {
        contrib += __shfl_xor(contrib, m, 64);
        vld     += __shfl_xor(vld, m, 64);
    }
    __shared__ float rl[4], rv[4];
    int lane = threadIdx.x & 63, w = threadIdx.x >> 6;
    if (lane == 0) { rl[w] = contrib; rv[w] = vld; }
    __syncthreads();
    if (threadIdx.x == 0) {
        float L = rl[0] + rl[1] + rl[2] + rl[3];
        float V = rv[0] + rv[1] + rv[2] + rv[3];
        atomicAdd(&accbuf[0], L);
        atomicAdd(&accbuf[1], V);
        __threadfence();
        unsigned t = atomicAdd((unsigned*)accbuf + 2, 1u);
        if (t == 31u) {                      // last block: all adds fenced+done
            float Ls = atomicAdd(&accbuf[0], 0.0f);
            float Vs = atomicAdd(&accbuf[1], 0.0f);
            out[0] = (Vs > 0.5f) ? (Ls / Vs) : 0.0f;
        }
    }
}

extern "C" void kernel_launch(void* const* d_in, const int* in_sizes, int n_in,
                              void* d_out, int out_size, void* d_ws, size_t ws_size,
                              hipStream_t stream)
{
    const void* Fin = d_in[0];
    const void* Lin = d_in[1];

    // ws layout (~2.7 MB)
    unsigned short* fbf = (unsigned short*)d_ws;                          // 2 MB bf16 copy
    int*   lab      = (int*)((char*)d_ws + (size_t)BB * DD * 2);          // 32 KB
    float* e_part   = (float*)((char*)lab + (size_t)BB * 4);              // NC*B floats (512 KB)
    float* diag     = e_part + (size_t)NC * BB;                           // B floats
    float* g        = diag + BB;                                          // 100*128 floats
    float* accbuf   = g + NCLS * DD;                                      // 3 slots

    supcon_convert<<<BB * DD / 4 / 256, 256, 0, stream>>>(Fin, Lin, fbf, lab, g, accbuf);

    supcon_classsum<<<NCLS * CS_CHUNKS, 128, 0, stream>>>(fbf, lab, g);

    dim3 grid(NC, BB / 128);
    supcon_main<<<grid, 256, 0, stream>>>(fbf, e_part, diag);

    supcon_reduce<<<32, 256, 0, stream>>>(e_part, fbf, lab, g, diag, accbuf, (float*)d_out);
}

// Round 7
// 126.237 us; speedup vs baseline: 1.4960x; 1.0983x over previous
//
#include <hip/hip_runtime.h>
#include <hip/hip_bf16.h>

// SupConLoss, B=8192, D=128, T=0.1. Output: single fp32 scalar.
//
// Pipeline (memset + 3 launches):
//   0) hipMemsetAsync  — zeroes class-sum buffer g + final accumulators
//      (graph-capture legal; harness's own reset uses hipMemsetAsync).
//   1) supcon_convert  — dtype detection (fp32 vs bf16 feats, i64 vs i32
//      labels) folded in; features -> bf16 ws copy (RTNE), labels -> int32;
//      ALSO accumulates class sums g[c][d] += bf16-rounded feature values
//      via global atomicAdd (1M independent pipelined atomics riding the
//      memory-bound sweep — replaces the 38us standalone classsum kernel).
//      Enables the p-via-dot identity: p_i = sum_{pos j} s_ij = a_i.g[lab_i]
//      (exact modulo fp32 reorder, ~1e-6 on the loss).
//   2) supcon_main     — fused bf16-MFMA GEMM (F.F^T) + exp accumulation
//      ONLY (epilogue = fma + exp2 + add per element; no labels, no masks).
//      LDS double-buffered 64-col B tiles via global_load_lds(16B), XOR
//      swizzle applied on the GLOBAL source address (linear LDS dest +
//      inverse-swz source + swz read = same involution). 2-phase pipeline:
//      stage(next) before compute(cur), one drain+barrier per tile.
//      ~34KB LDS -> 4 blocks/CU resident. Diagonal raw dot s_ii captured
//      once per row. FROZEN from r6 for clean counter diagnosis.
//   3) supcon_reduce   — e partials + p_i = a_i.g[lab_i] dot (all 128 dims)
//      -> loss. n_i from exact label histogram. Diagonal terms removed
//      exactly (e: same exp2 instruction on same input; p: subtract diag).
//      Last-block-atomic finalization (ticket zeroed by memset each run ->
//      graph-replay safe).
//
// Math: with ANY fixed shift M, per row i:
//   mean_log_prob_i = 10*p_i/n_i - M - log(sum_{j!=i} exp(s_ij - M))
// (shift cancels; M=10.5 >= max s_ij for unit-norm). exp folded to exp2.
//
// History:
//  r1: __launch_bounds__(256,4) forced VGPR=64 -> spill, FETCH 9.7->646MB,
//      46->215us. Never clamp below the live set.
//  r2: NC=16 + n_acc removal: main ~46 -> ~36us. Fixed 41us/268MB harness
//      workspace-poison fill in the timed region (uncontrollable floor).
//  r3: no-LDS direct-L2 reads: main 68.7us. Latency-bound serial chain.
//  r4: 2-phase pipelined staging: main ~35us. Epilogue-VALU bound.
//  r5: class-sum identity; classsum v1 (16-block LDS-atomic chain): 88us.
//      reduce p-dot covered 64/128 dims -> +0.0625 bias. Fixed in r6.
//  r6: classsum v2 (class-parallel uniform scan): still ~38us — 256
//      serially-dependent uniform loads per block. Both main (~35) and
//      classsum (~38) hidden below the 41us fill in top-5. This round:
//      classsum folded into convert as pipelined global atomics; main
//      FROZEN so its counters surface next round.

#define BB 8192
#define DD 128
#define NCLS 100
#define NC 16                // column chunks (grid.x): 1024 blocks, 4/CU
#define COLCHUNK (BB / NC)   // 512 cols per WG
#define TILEC 64             // cols per staged tile (16KB)
#define ITERS (COLCHUNK / TILEC)
#define TEMP_INV 10.0f
#define MSHIFT 10.5f
#define C1F 14.426950408889634f    /* 10*log2(e)    */
#define C2F -15.148297929334116f   /* -10.5*log2(e) */

typedef __bf16 bf16x8 __attribute__((ext_vector_type(8)));
typedef float floatx4 __attribute__((ext_vector_type(4)));

__device__ inline float fast_exp2(float x) {
#if __has_builtin(__builtin_amdgcn_exp2f)
    return __builtin_amdgcn_exp2f(x);
#else
    return exp2f(x);
#endif
}

__device__ inline unsigned short f2bf(float f) {           // RTNE fp32->bf16
    unsigned u = __float_as_uint(f);
    return (unsigned short)((u + 0x7FFFu + ((u >> 16) & 1u)) >> 16);
}

__device__ inline float bf2f(unsigned short s) {
    return __uint_as_float(((unsigned)s) << 16);
}

__device__ inline void gload_lds16(const void* g, void* l) {
    __builtin_amdgcn_global_load_lds(
        (const __attribute__((address_space(1))) void*)g,
        (__attribute__((address_space(3))) void*)l, 16, 0, 0);
}

// ---- 1) canonicalize (+ detect + fused class-sum atomics) ----
__global__ __launch_bounds__(256) void supcon_convert(
    const void* __restrict__ fin, const void* __restrict__ lin,
    unsigned short* __restrict__ fbf, int* __restrict__ lab,
    float* __restrict__ g)
{
    // Per-wave dtype detection: every wave reads the same 128-short feature
    // header and 128-int label header, butterfly-reduces across its own 64
    // lanes -> every thread holds the verdict, no LDS/sync needed.
    int lane = threadIdx.x & 63;
    unsigned ue = ((unsigned)((const unsigned short*)fin)[2 * lane]) << 16;
    float fe = __uint_as_float(ue);
    float ve = fe * fe;
    int odd_or = ((const int*)lin)[2 * lane + 1];
#pragma unroll
    for (int m = 1; m < 64; m <<= 1) {
        ve += __shfl_xor(ve, m, 64);
        odd_or |= __shfl_xor(odd_or, m, 64);
    }
    // true bf16 unit rows: sum sq of 64 even slots of row 0 is ~0.5.
    bool f_bf16 = (ve > 0.05f) && (ve < 4.0f);   // NaN-safe: NaN -> false
    bool l_i64  = (odd_or == 0);

    int gid = blockIdx.x * 256 + threadIdx.x;    // 262144 threads x 4 elements
    int row = gid >> 5;                          // 32 threads per 128-dim row
    int d0  = (gid & 31) * 4;

    const int* L = (const int*)lin;
    int c = l_i64 ? L[2 * row] : L[row];         // label of this thread's row

    float4 vf;                                   // bf16-rounded fp32 values
    if (!f_bf16) {
        float4 v = ((const float4*)fin)[gid];
        ushort4 o;
        o.x = f2bf(v.x); o.y = f2bf(v.y); o.z = f2bf(v.z); o.w = f2bf(v.w);
        ((ushort4*)fbf)[gid] = o;
        vf.x = bf2f(o.x); vf.y = bf2f(o.y); vf.z = bf2f(o.z); vf.w = bf2f(o.w);
    } else {
        ushort4 o = ((const ushort4*)fin)[gid];
        ((ushort4*)fbf)[gid] = o;
        vf.x = bf2f(o.x); vf.y = bf2f(o.y); vf.z = bf2f(o.z); vf.w = bf2f(o.w);
    }

    // Fused class-sum: 4 independent pipelined global atomics per thread,
    // riding under this kernel's memory-bound sweep.
    float* gc = g + c * DD + d0;
    atomicAdd(gc + 0, vf.x);
    atomicAdd(gc + 1, vf.y);
    atomicAdd(gc + 2, vf.z);
    atomicAdd(gc + 3, vf.w);

    if (blockIdx.x < 32) {
        int li = blockIdx.x * 256 + threadIdx.x;
        lab[li] = l_i64 ? L[2 * li] : L[li];
    }
}

// Stage one 64-col B tile (16KB) into ldsB[bsel] via global_load_lds.
// LDS dest is LINEAR (wave-uniform base + lane*16, hardware rule); the XOR
// swizzle is applied to the SOURCE address. Dest slot d of row r receives
// source chunk d^(r&15); the swizzled ds_read of chunk k at slot k^(r&15)
// therefore returns chunk k — identical values to a swizzled ds_write path.
#define STAGE_B(itx, bsel)                                                   \
    {                                                                        \
        const unsigned char* gB =                                            \
            Fbc + (size_t)(colchunkbase + (itx) * TILEC) * 256;              \
        unsigned char* lb = &ldsB[bsel][0];                                  \
        _Pragma("unroll")                                                    \
        for (int r = 0; r < 4; ++r) {                                        \
            int off = r * 4096 + tid * 16;                                   \
            int row = off >> 8;                                              \
            int gg  = (off >> 4) & 15;                                       \
            int gs  = gg ^ (row & 15);                                       \
            gload_lds16(gB + row * 256 + gs * 16, lb + off);                 \
        }                                                                    \
    }

// ---- 2) fused GEMM + exp partials (2-phase pipelined, e-only epilogue) ----
// FROZEN from r6 for clean counter diagnosis next round.
__global__ __launch_bounds__(256, 2) void supcon_main(
    const unsigned short* __restrict__ Fb,
    float* __restrict__ e_part, float* __restrict__ diag)
{
    __shared__ unsigned char ldsB[2][16384];      // double-buffered 64-col tiles
    __shared__ float red[128][2];

    const int tid  = threadIdx.x;
    const int lane = tid & 63;
    const int wid  = tid >> 6;
    const int wrow = wid >> 1;
    const int wcol = wid & 1;
    const int quad = lane >> 4;
    const int l16  = lane & 15;

    const int chunk   = blockIdx.x;
    const int rowbase = blockIdx.y * 128;
    const int colchunkbase = chunk * COLCHUNK;

    const unsigned char* Fbc = (const unsigned char*)Fb;

    // Prologue: stage tile 0; A-frag loads (direct from L2) overlap it.
    STAGE_B(0, 0);

    bf16x8 afrag[4][4];
#pragma unroll
    for (int ti = 0; ti < 4; ++ti) {
        int row = rowbase + wrow * 64 + ti * 16 + l16;
        const unsigned char* gA = Fbc + (size_t)row * 256 + quad * 16;
#pragma unroll
        for (int k = 0; k < 4; ++k)
            afrag[ti][k] = *(const bf16x8*)(gA + k * 64);
    }

    float e_acc[16];
#pragma unroll
    for (int i = 0; i < 16; ++i) e_acc[i] = 0.0f;

    __syncthreads();   // drains tile-0 staging (vmcnt(0)) + barrier

    int cur = 0;
    for (int it = 0; it < ITERS; ++it) {
        // Issue next tile's stage FIRST: latency hides under this tile's
        // MFMA+epilogue.
        if (it + 1 < ITERS) STAGE_B(it + 1, cur ^ 1);

        int colbase = colchunkbase + it * TILEC;
        const unsigned char* lb = &ldsB[cur][0];

#pragma unroll
        for (int tj = 0; tj < 2; ++tj) {
            int coll = wcol * 32 + tj * 16 + l16;   // B[n=l16][k=quad*8+j]
            bf16x8 bfrag[4];
#pragma unroll
            for (int k = 0; k < 4; ++k) {
                int gg = k * 4 + quad;
                int gs = gg ^ (coll & 15);
                bfrag[k] = *(const bf16x8*)(lb + coll * 256 + gs * 16);
            }
            floatx4 acc[4];
#pragma unroll
            for (int ti = 0; ti < 4; ++ti) acc[ti] = (floatx4){0.f, 0.f, 0.f, 0.f};
#pragma unroll
            for (int k = 0; k < 4; ++k)
#pragma unroll
                for (int ti = 0; ti < 4; ++ti)
                    acc[ti] = __builtin_amdgcn_mfma_f32_16x16x32_bf16(
                        afrag[ti][k], bfrag[k], acc[ti], 0, 0, 0);

            // Diagonal capture: wave-uniform, rare (once per 64 diag cols).
            // Static indexing of acc (rule: no runtime ext_vector index).
            {
                int ctb = colbase + wcol * 32 + tj * 16;
                unsigned u = (unsigned)(ctb - (rowbase + wrow * 64));
                if (u < 64u) {
#pragma unroll
                    for (int ti2 = 0; ti2 < 4; ++ti2) {
                        if (u == (unsigned)(ti2 * 16)) {
#pragma unroll
                            for (int r = 0; r < 4; ++r)
                                if (l16 == quad * 4 + r)
                                    diag[ctb + l16] = acc[ti2][r];
                        }
                    }
                }
            }

#pragma unroll
            for (int ti = 0; ti < 4; ++ti) {
#pragma unroll
                for (int r = 0; r < 4; ++r) {
                    // C/D: D[row=quad*4+r][col=l16] (m89/m91 verified)
                    // 2 VALU + 1 trans per elem: fma, exp2, add.
                    float a = acc[ti][r];                        // raw dot
                    e_acc[ti * 4 + r] += fast_exp2(__builtin_fmaf(a, C1F, C2F));
                }
            }
        }
        __syncthreads();   // drain next-tile loads + all waves done reading cur
        cur ^= 1;
    }

    // reduce across 16 column-lanes (xor over lane bits 0..3)
#pragma unroll
    for (int i = 0; i < 16; ++i) {
        float e = e_acc[i];
#pragma unroll
        for (int m = 1; m < 16; m <<= 1) e += __shfl_xor(e, m, 64);
        if (l16 == 0) {
            int row_local = wrow * 64 + (i >> 2) * 16 + quad * 4 + (i & 3);
            red[row_local][wcol] = e;
        }
    }
    __syncthreads();

    if (tid < 128) {
        size_t idx = (size_t)chunk * BB + (rowbase + tid);
        e_part[idx] = red[tid][0] + red[tid][1];
    }
}

// ---- 3) e partials + p-dot -> scalar loss ----
__global__ __launch_bounds__(256) void supcon_reduce(
    const float* __restrict__ e_part, const unsigned short* __restrict__ Fb,
    const int* __restrict__ labels, const float* __restrict__ g,
    const float* __restrict__ diag,
    float* __restrict__ accbuf, float* __restrict__ out)
{
    // Exact per-class counts over the whole batch (labels in [0,100)).
    __shared__ int cnt[128];
    if (threadIdx.x < 128) cnt[threadIdx.x] = 0;
    __syncthreads();
    for (int i = threadIdx.x; i < BB; i += 256)
        atomicAdd(&cnt[labels[i]], 1);
    __syncthreads();

    int row = blockIdx.x * 256 + threadIdx.x;    // grid 32
    float e = 0.f;
#pragma unroll
    for (int c = 0; c < NC; ++c)
        e += e_part[(size_t)c * BB + row];

    int cls = labels[row];

    // p_i = a_i . g[lab_i]  (bf16-rounded features, fp32 class sums).
    // 16 x uint4 = all 128 dims.
    const unsigned short* fr = Fb + (size_t)row * DD;
    const float* gr = g + cls * DD;
    float p0 = 0.f, p1 = 0.f;
#pragma unroll
    for (int q = 0; q < 16; ++q) {
        uint4  u  = ((const uint4*)fr)[q];        // 8 bf16
        float4 ga = ((const float4*)gr)[2 * q];
        float4 gb = ((const float4*)gr)[2 * q + 1];
        p0 = __builtin_fmaf(__uint_as_float(u.x << 16),          ga.x, p0);
        p1 = __builtin_fmaf(__uint_as_float(u.x & 0xFFFF0000u),  ga.y, p1);
        p0 = __builtin_fmaf(__uint_as_float(u.y << 16),          ga.z, p0);
        p1 = __builtin_fmaf(__uint_as_float(u.y & 0xFFFF0000u),  ga.w, p1);
        p0 = __builtin_fmaf(__uint_as_float(u.z << 16),          gb.x, p0);
        p1 = __builtin_fmaf(__uint_as_float(u.z & 0xFFFF0000u),  gb.y, p1);
        p0 = __builtin_fmaf(__uint_as_float(u.w << 16),          gb.z, p0);
        p1 = __builtin_fmaf(__uint_as_float(u.w & 0xFFFF0000u),  gb.w, p1);
    }
    float p = p0 + p1;

    // exact diagonal removal (e: same exp2 instruction on same input as main)
    float d = diag[row];
    e -= fast_exp2(__builtin_fmaf(d, C1F, C2F));
    p -= d;
    int n_i = cnt[cls] - 1;                      // integer-exact positive count

    float contrib = 0.f, vld = 0.f;
    if (n_i > 0) {
        vld = 1.0f;
        contrib = -(p * TEMP_INV / (float)n_i - MSHIFT - logf(e));
    }
#pragma unroll
    for (int m = 1; m < 64; m <<= 1) {
        contrib += __shfl_xor(contrib, m, 64);
        vld     += __shfl_xor(vld, m, 64);
    }
    __shared__ float rl[4], rv[4];
    int lane = threadIdx.x & 63, w = threadIdx.x >> 6;
    if (lane == 0) { rl[w] = contrib; rv[w] = vld; }
    __syncthreads();
    if (threadIdx.x == 0) {
        float L = rl[0] + rl[1] + rl[2] + rl[3];
        float V = rv[0] + rv[1] + rv[2] + rv[3];
        atomicAdd(&accbuf[0], L);
        atomicAdd(&accbuf[1], V);
        __threadfence();
        unsigned t = atomicAdd((unsigned*)accbuf + 2, 1u);
        if (t == 31u) {                      // last block: all adds fenced+done
            float Ls = atomicAdd(&accbuf[0], 0.0f);
            float Vs = atomicAdd(&accbuf[1], 0.0f);
            out[0] = (Vs > 0.5f) ? (Ls / Vs) : 0.0f;
        }
    }
}

extern "C" void kernel_launch(void* const* d_in, const int* in_sizes, int n_in,
                              void* d_out, int out_size, void* d_ws, size_t ws_size,
                              hipStream_t stream)
{
    const void* Fin = d_in[0];
    const void* Lin = d_in[1];

    // ws layout (~2.7 MB)
    unsigned short* fbf = (unsigned short*)d_ws;                          // 2 MB bf16 copy
    int*   lab      = (int*)((char*)d_ws + (size_t)BB * DD * 2);          // 32 KB
    float* e_part   = (float*)((char*)lab + (size_t)BB * 4);              // NC*B floats (512 KB)
    float* diag     = e_part + (size_t)NC * BB;                           // B floats
    float* g        = diag + BB;                                          // 100*128 floats
    float* accbuf   = g + NCLS * DD;                                      // 3 slots (contiguous after g)

    // Zero g + accbuf (graph-capture legal; stream-ordered before convert).
    hipMemsetAsync(g, 0, (size_t)(NCLS * DD + 3) * 4, stream);

    supcon_convert<<<BB * DD / 4 / 256, 256, 0, stream>>>(Fin, Lin, fbf, lab, g);

    dim3 grid(NC, BB / 128);
    supcon_main<<<grid, 256, 0, stream>>>(fbf, e_part, diag);

    supcon_reduce<<<32, 256, 0, stream>>>(e_part, fbf, lab, g, diag, accbuf, (float*)d_out);
}